// Round 1
// baseline (910.319 us; speedup 1.0000x reference)
//
#include <hip/hip_runtime.h>
#include <hip/hip_bf16.h>

#define B_ 128
#define L_ 1024
#define D_ 256
#define T_ 64
// labels: START=0, END=1, PAD=2

__device__ __forceinline__ float bcastf(float v, int lane) {
  return __builtin_bit_cast(float, __builtin_amdgcn_readlane(__builtin_bit_cast(int, v), lane));
}

// ---------------- K1: emissions[r][j] = embed[x[r]] . W[:,j] + b[j]  (bf16 out) ----
__global__ __launch_bounds__(256) void k_emis(const int* __restrict__ x,
                                              const float* __restrict__ embed,
                                              const float* __restrict__ W,
                                              const float* __restrict__ bias,
                                              __hip_bfloat16* __restrict__ emis) {
  __shared__ float Wl[D_ * T_];  // 64 KB
  {
    const float4* W4 = (const float4*)W;
    float4* Wl4 = (float4*)Wl;
#pragma unroll
    for (int t = 0; t < (D_ * T_ / 4) / 256; t++)
      Wl4[t * 256 + threadIdx.x] = W4[t * 256 + threadIdx.x];
  }
  __syncthreads();
  const int wave = threadIdx.x >> 6, lane = threadIdx.x & 63;
  const float bj = bias[lane];
  // block covers 128 rows; wave covers 32, in groups of 4
  const int rbase = blockIdx.x * 128 + wave * 32;
  for (int g = 0; g < 8; g++) {
    const int r = rbase + g * 4;
    // wave-uniform row pointers -> scalar loads of embed values
    const float* er0 = embed + (size_t)((unsigned)__builtin_amdgcn_readfirstlane(x[r + 0])) * D_;
    const float* er1 = embed + (size_t)((unsigned)__builtin_amdgcn_readfirstlane(x[r + 1])) * D_;
    const float* er2 = embed + (size_t)((unsigned)__builtin_amdgcn_readfirstlane(x[r + 2])) * D_;
    const float* er3 = embed + (size_t)((unsigned)__builtin_amdgcn_readfirstlane(x[r + 3])) * D_;
    float a0 = bj, a1 = bj, a2 = bj, a3 = bj;
#pragma unroll 64
    for (int d = 0; d < D_; d++) {
      const float w = Wl[d * T_ + lane];
      a0 = fmaf(er0[d], w, a0);
      a1 = fmaf(er1[d], w, a1);
      a2 = fmaf(er2[d], w, a2);
      a3 = fmaf(er3[d], w, a3);
    }
    emis[(size_t)(r + 0) * T_ + lane] = __float2bfloat16(a0);
    emis[(size_t)(r + 1) * T_ + lane] = __float2bfloat16(a1);
    emis[(size_t)(r + 2) * T_ + lane] = __float2bfloat16(a2);
    emis[(size_t)(r + 3) * T_ + lane] = __float2bfloat16(a3);
  }
}

// ---------------- K2: CRF forward recursion, one wave per batch ----------------
// alpha_new_j = M + log( sum_i exp(alpha_i - M) * E[i][j] ) + emit_j,  E = exp(trans)
__global__ __launch_bounds__(64) void k_crf(const __hip_bfloat16* __restrict__ emis,
                                            const float* __restrict__ trans,
                                            float* __restrict__ logz) {
  const int b = blockIdx.x, lane = threadIdx.x;
  float Ec[64];  // column `lane` of exp(trans), i-indexed, kept in VGPRs
#pragma unroll
  for (int i = 0; i < 64; i++) Ec[i] = __expf(trans[i * T_ + lane]);
  const __hip_bfloat16* em = emis + (size_t)b * (L_ * T_);
  float alpha = trans[lane] + __bfloat162float(em[lane]);  // trans[START][j] + emit0
  float nx1 = __bfloat162float(em[T_ + lane]);
  float nx2 = __bfloat162float(em[2 * T_ + lane]);
  for (int l = 1; l < L_; l++) {
    const float emit = nx1;
    nx1 = nx2;
    if (l + 2 < L_) nx2 = __bfloat162float(em[(size_t)(l + 2) * T_ + lane]);
    const float M = bcastf(alpha, 3);  // tag 3 is a regular (never-blocked) tag
    const float p = __expf(alpha - M);
    float s0 = 0.f, s1 = 0.f, s2 = 0.f, s3 = 0.f;
#pragma unroll
    for (int i = 0; i < 64; i += 4) {
      s0 = fmaf(bcastf(p, i + 0), Ec[i + 0], s0);
      s1 = fmaf(bcastf(p, i + 1), Ec[i + 1], s1);
      s2 = fmaf(bcastf(p, i + 2), Ec[i + 2], s2);
      s3 = fmaf(bcastf(p, i + 3), Ec[i + 3], s3);
    }
    float S = (s0 + s1) + (s2 + s3);
    S = fmaxf(S, 1e-37f);  // blocked columns: finite floor instead of -inf
    alpha = M + __logf(S) + emit;
  }
  // log_z = logsumexp_j(alpha_j + trans[j][END])
  const float v = alpha + trans[lane * T_ + 1];
  float m = v;
#pragma unroll
  for (int off = 32; off > 0; off >>= 1) m = fmaxf(m, __shfl_xor(m, off));
  float s = __expf(v - m);
#pragma unroll
  for (int off = 32; off > 0; off >>= 1) s += __shfl_xor(s, off);
  if (lane == 0) logz[b] = m + __logf(s);
}

// ---------------- K3: gold path score per batch ----------------
__global__ __launch_bounds__(256) void k_scores(const int* __restrict__ tags,
                                                const __hip_bfloat16* __restrict__ emis,
                                                const float* __restrict__ trans,
                                                float* __restrict__ score) {
  const int b = blockIdx.x;
  const int* tg = tags + (size_t)b * L_;
  const __hip_bfloat16* em = emis + (size_t)b * (L_ * T_);
  float acc = 0.f;
  for (int l = threadIdx.x; l < L_; l += 256) {
    const int t = tg[l];
    acc += __bfloat162float(em[(size_t)l * T_ + t]);
    if (l < L_ - 1) acc += trans[t * T_ + tg[l + 1]];
  }
#pragma unroll
  for (int off = 32; off > 0; off >>= 1) acc += __shfl_xor(acc, off);
  __shared__ float red[4];
  if ((threadIdx.x & 63) == 0) red[threadIdx.x >> 6] = acc;
  __syncthreads();
  if (threadIdx.x == 0) {
    float s = red[0] + red[1] + red[2] + red[3];
    s += trans[0 * T_ + tg[0]];        // trans[START, tags[0]]
    s += trans[tg[L_ - 1] * T_ + 1];   // trans[tags[-1], END]
    score[b] = s;
  }
}

// ---------------- K4: out = -sum_b (score_b - logz_b) ----------------
__global__ __launch_bounds__(128) void k_final(const float* __restrict__ score,
                                               const float* __restrict__ logz,
                                               float* __restrict__ out) {
  const int t = threadIdx.x;
  float v = score[t] - logz[t];
#pragma unroll
  for (int off = 32; off > 0; off >>= 1) v += __shfl_xor(v, off);
  __shared__ float r[2];
  if ((t & 63) == 0) r[t >> 6] = v;
  __syncthreads();
  if (t == 0) out[0] = -(r[0] + r[1]);
}

extern "C" void kernel_launch(void* const* d_in, const int* in_sizes, int n_in,
                              void* d_out, int out_size, void* d_ws, size_t ws_size,
                              hipStream_t stream) {
  const int* x = (const int*)d_in[0];
  const int* tags = (const int*)d_in[1];
  // d_in[2] = mask, ignored by the reference
  const float* embed = (const float*)d_in[3];
  const float* W = (const float*)d_in[4];
  const float* bias = (const float*)d_in[5];
  const float* trans = (const float*)d_in[6];

  char* ws = (char*)d_ws;
  __hip_bfloat16* emis = (__hip_bfloat16*)ws;                       // 16,777,216 B
  float* logz = (float*)(ws + (size_t)B_ * L_ * T_ * sizeof(__hip_bfloat16));
  float* score = logz + B_;
  float* out = (float*)d_out;

  k_emis<<<(B_ * L_) / 128, 256, 0, stream>>>(x, embed, W, bias, emis);
  k_crf<<<B_, 64, 0, stream>>>(emis, trans, logz);
  k_scores<<<B_, 256, 0, stream>>>(tags, emis, trans, score);
  k_final<<<1, 128, 0, stream>>>(score, logz, out);
}